// Round 14
// baseline (300.879 us; speedup 1.0000x reference)
//
#include <hip/hip_runtime.h>
#include <cstdint>
#include <cstddef>

// ---------------- constants ----------------
#define T_TOK 2048
#define HID   4096
#define NQH   32
#define NKVH  8
#define HD    128
#define QKV_N 6144   // 4096 q + 1024 k + 1024 v

typedef __bf16 bf16x8 __attribute__((ext_vector_type(8)));
typedef __bf16 bf16x4 __attribute__((ext_vector_type(4)));
typedef float  f32x4  __attribute__((ext_vector_type(4)));
typedef float  f32x16 __attribute__((ext_vector_type(16)));

#define AS1 __attribute__((address_space(1)))
#define AS3 __attribute__((address_space(3)))

__device__ __forceinline__ void gll16(const void* g, void* l) {
  __builtin_amdgcn_global_load_lds((const AS1 void*)g, (AS3 void*)l, 16, 0, 0);
}

// ------- fused prologue: hidden fp32->bf16 convert + w_qkv transpose --------
// blocks < 8192: convert (exact cover of 2048*4096/4 float4s).
// blocks >= 8192: 64x64 transpose tile of w_qkv [4096][6144] -> wqkv_t bf16.
__global__ __launch_bounds__(256) void k_prep(const float* __restrict__ hidden,
                                              __bf16* __restrict__ hidden_b,
                                              const float* __restrict__ wqkv,
                                              __bf16* __restrict__ wqkv_t) {
  __shared__ float tile[64][65];
  const int tid = threadIdx.x;
  if (blockIdx.x < 8192) {
    int i = blockIdx.x * 256 + tid;
    float4 v = ((const float4*)hidden)[i];
    bf16x4 o;
    o[0] = (__bf16)v.x; o[1] = (__bf16)v.y; o[2] = (__bf16)v.z; o[3] = (__bf16)v.w;
    ((bf16x4*)hidden_b)[i] = o;
    return;
  }
  const int tb = blockIdx.x - 8192;          // 0..6143
  const int c0 = (tb % 96) * 64, r0 = (tb / 96) * 64;   // C=6144, R=4096
  const int ty = tid >> 4, tx = tid & 15;
#pragma unroll
  for (int k = 0; k < 4; ++k) {
    float4 v = *(const float4*)&wqkv[(size_t)(r0 + ty + k * 16) * QKV_N + c0 + tx * 4];
    tile[ty + k * 16][tx * 4 + 0] = v.x;
    tile[ty + k * 16][tx * 4 + 1] = v.y;
    tile[ty + k * 16][tx * 4 + 2] = v.z;
    tile[ty + k * 16][tx * 4 + 3] = v.w;
  }
  __syncthreads();
  const int c = tid >> 2, rq = tid & 3;
#pragma unroll
  for (int h = 0; h < 2; ++h) {
    bf16x8 o;
#pragma unroll
    for (int i = 0; i < 8; ++i) o[i] = (__bf16)tile[rq * 16 + h * 8 + i][c];
    *(bf16x8*)&wqkv_t[(size_t)(c0 + c) * HID + r0 + rq * 16 + h * 8] = o;
  }
}

// ---------------- 4-phase bf16 GEMM, BM=128 x BN=64*NFR (known-good loop) ---
// NORM=true (gemm1, NFR=6): fused epilogue -- acc -> LDS bf16 tile [128][394],
// then RMSNorm+RoPE for q/k heads (BN=384 = 3 whole heads/block; block rows =
// 128 whole tokens) writing qo/ko, and coalesced V-transpose writing vto.
// NORM=false (gemm2): plain OUT-typed C write.
template <int NFR, typename OUT, bool NORM>
__global__ __launch_bounds__(512, 2) void k_gemm8(const __bf16* __restrict__ A,
                                                  const __bf16* __restrict__ Bt,
                                                  OUT* __restrict__ C,
                                                  int N, int K,
                                                  const int* __restrict__ pos,
                                                  const float* __restrict__ qw,
                                                  const float* __restrict__ kw,
                                                  __bf16* __restrict__ qo,
                                                  __bf16* __restrict__ ko,
                                                  __bf16* __restrict__ vto) {
  constexpr int BN   = 64 * NFR;
  constexpr int WN   = 16 * NFR;
  constexpr int NB   = NFR / 2;
  constexpr int NH   = NFR / 2;
  constexpr int BREG = BN * 64;
  constexpr int BUFSZ = 16384 + 2 * BREG;
  __shared__ alignas(16) char ldsb[2 * BUFSZ];
  const int tid = threadIdx.x;
  const int lane = tid & 63, w = tid >> 6;
  const int l16 = lane & 15, lg = lane >> 4;
  const int wm = w >> 2, wn = w & 3;

  const int x = blockIdx.x & 7, idx = blockIdx.x >> 3;
  const int bm = (x & 1) * 8 + (idx & 7);
  const int bn = (x >> 1) * 4 + (idx >> 3);

  const int rA = tid >> 2, pA = tid & 3;
  const __bf16* asrc = A + (size_t)(bm * 128 + rA) * K + ((pA ^ ((rA >> 1) & 3)) * 8);
  const __bf16* bsrc = Bt + (size_t)(bn * BN + rA) * K + ((pA ^ ((rA >> 1) & 3)) * 8);

#define RA_(buf, mk) (ldsb + (buf) * BUFSZ + (mk) * 8192)
#define RB_(buf, mk) (ldsb + (buf) * BUFSZ + 16384 + (mk) * BREG)
#define STG_A(buf, mk, kk) { gll16(asrc + (kk) + (mk) * 32, RA_(buf, mk) + w * 1024); }
#define STG_B(buf, mk, kk) { _Pragma("unroll") \
    for (int j = 0; j < NB; ++j) \
      gll16(bsrc + (size_t)j * 128 * K + (kk) + (mk) * 32, RB_(buf, mk) + j * 8192 + w * 1024); }
#define FRAG(base, row) (*(const bf16x8*)((base) + (row) * 64 + ((lg ^ (((row) >> 1) & 3)) << 4)))
#define WAITN() { if constexpr (NFR == 6) asm volatile("s_waitcnt vmcnt(4)" ::: "memory"); \
                  else                    asm volatile("s_waitcnt vmcnt(3)" ::: "memory"); }

  f32x4 acc[4][NFR] = {};
  const int nkt = K >> 6;

  STG_A(0, 0, 0); STG_B(0, 0, 0); STG_A(0, 1, 0); STG_B(0, 1, 0);

  for (int t = 0; t < nkt - 1; ++t) {
    const int cur = t & 1, nxt = cur ^ 1;
    const int kn = (t + 1) * 64;
    bf16x8 af[4], bf_[NH];

    STG_A(nxt, 0, kn);
    WAITN();
    __builtin_amdgcn_s_barrier();
    __builtin_amdgcn_sched_barrier(0);
#pragma unroll
    for (int i = 0; i < 4; ++i) af[i] = FRAG(RA_(cur, 0), wm * 64 + i * 16 + l16);
#pragma unroll
    for (int n = 0; n < NH; ++n) bf_[n] = FRAG(RB_(cur, 0), wn * WN + n * 16 + l16);
    __builtin_amdgcn_s_setprio(1);
#pragma unroll
    for (int i = 0; i < 4; ++i)
#pragma unroll
      for (int n = 0; n < NH; ++n)
        acc[i][n] = __builtin_amdgcn_mfma_f32_16x16x32_bf16(af[i], bf_[n], acc[i][n], 0, 0, 0);
    __builtin_amdgcn_s_setprio(0);
    __builtin_amdgcn_s_barrier();

#pragma unroll
    for (int n = 0; n < NH; ++n) bf_[n] = FRAG(RB_(cur, 0), wn * WN + (NH + n) * 16 + l16);
    STG_B(nxt, 0, kn);
    __builtin_amdgcn_s_barrier();
    __builtin_amdgcn_s_setprio(1);
#pragma unroll
    for (int i = 0; i < 4; ++i)
#pragma unroll
      for (int n = 0; n < NH; ++n)
        acc[i][NH + n] = __builtin_amdgcn_mfma_f32_16x16x32_bf16(af[i], bf_[n], acc[i][NH + n], 0, 0, 0);
    __builtin_amdgcn_s_setprio(0);
    __builtin_amdgcn_s_barrier();

    STG_A(nxt, 1, kn);
    WAITN();
    __builtin_amdgcn_s_barrier();
    __builtin_amdgcn_sched_barrier(0);
#pragma unroll
    for (int i = 0; i < 4; ++i) af[i] = FRAG(RA_(cur, 1), wm * 64 + i * 16 + l16);
#pragma unroll
    for (int n = 0; n < NH; ++n) bf_[n] = FRAG(RB_(cur, 1), wn * WN + n * 16 + l16);
    __builtin_amdgcn_s_setprio(1);
#pragma unroll
    for (int i = 0; i < 4; ++i)
#pragma unroll
      for (int n = 0; n < NH; ++n)
        acc[i][n] = __builtin_amdgcn_mfma_f32_16x16x32_bf16(af[i], bf_[n], acc[i][n], 0, 0, 0);
    __builtin_amdgcn_s_setprio(0);
    __builtin_amdgcn_s_barrier();

#pragma unroll
    for (int n = 0; n < NH; ++n) bf_[n] = FRAG(RB_(cur, 1), wn * WN + (NH + n) * 16 + l16);
    STG_B(nxt, 1, kn);
    __builtin_amdgcn_s_barrier();
    __builtin_amdgcn_s_setprio(1);
#pragma unroll
    for (int i = 0; i < 4; ++i)
#pragma unroll
      for (int n = 0; n < NH; ++n)
        acc[i][NH + n] = __builtin_amdgcn_mfma_f32_16x16x32_bf16(af[i], bf_[n], acc[i][NH + n], 0, 0, 0);
    __builtin_amdgcn_s_setprio(0);
    __builtin_amdgcn_s_barrier();
  }

  asm volatile("s_waitcnt vmcnt(0)" ::: "memory");
  __builtin_amdgcn_s_barrier();
  __builtin_amdgcn_sched_barrier(0);
  {
    const int cur = (nkt - 1) & 1;
#pragma unroll
    for (int mk = 0; mk < 2; ++mk) {
      bf16x8 aa[4], bb[NFR];
#pragma unroll
      for (int i = 0; i < 4; ++i) aa[i] = FRAG(RA_(cur, mk), wm * 64 + i * 16 + l16);
#pragma unroll
      for (int n = 0; n < NFR; ++n) bb[n] = FRAG(RB_(cur, mk), wn * WN + n * 16 + l16);
#pragma unroll
      for (int i = 0; i < 4; ++i)
#pragma unroll
        for (int n = 0; n < NFR; ++n)
          acc[i][n] = __builtin_amdgcn_mfma_f32_16x16x32_bf16(aa[i], bb[n], acc[i][n], 0, 0, 0);
    }
  }
#undef RA_
#undef RB_
#undef STG_A
#undef STG_B
#undef FRAG
#undef WAITN

  if constexpr (!NORM) {
#pragma unroll
    for (int mi = 0; mi < 4; ++mi)
#pragma unroll
      for (int ni = 0; ni < NFR; ++ni) {
        int row = bm * 128 + wm * 64 + mi * 16 + lg * 4;
        int col = bn * BN + wn * WN + ni * 16 + l16;
#pragma unroll
        for (int r = 0; r < 4; ++r)
          C[(size_t)(row + r) * N + col] = (OUT)acc[mi][ni][r];
      }
  } else {
    // ---- fused RMSNorm+RoPE+Vt epilogue (NFR==6: 3 heads x 128 tokens) ----
    __syncthreads();                       // staging LDS reads done in all waves
    __bf16 (*tile)[394] = (__bf16(*)[394])ldsb;   // 128*394*2 = 100864 B
#pragma unroll
    for (int mi = 0; mi < 4; ++mi)
#pragma unroll
      for (int ni = 0; ni < NFR; ++ni) {
        int row = wm * 64 + mi * 16 + lg * 4;
        int col = wn * WN + ni * 16 + l16;
#pragma unroll
        for (int r = 0; r < 4; ++r)
          tile[row + r][col] = (__bf16)acc[mi][ni][r];
      }
    __syncthreads();
    // q/k: wave w owns tokens w*16..w*16+15; 3 heads each
    const float qw1 = qw[lane], qw2 = qw[lane + 64];
    const float kw1 = kw[lane], kw2 = kw[lane + 64];
    const float iexp = expf((float)lane * -0.21586735246819178f);
    for (int tr = 0; tr < 16; ++tr) {
      const int trow = w * 16 + tr;
      const int tok = bm * 128 + trow;
      const float fr = (float)pos[tok] * iexp;
      const float cs = cosf(fr), sn = sinf(fr);
#pragma unroll
      for (int hh = 0; hh < 3; ++hh) {
        const int hid = bn * 3 + hh;       // global head slot 0..47
        if (hid >= 40) continue;           // v handled below
        float x1 = (float)tile[trow][hh * 128 + lane];
        float x2 = (float)tile[trow][hh * 128 + 64 + lane];
        float ss = x1 * x1 + x2 * x2;
#pragma unroll
        for (int m = 32; m >= 1; m >>= 1) ss += __shfl_xor(ss, m);
        float rinv = rsqrtf(ss * (1.0f / 128.0f) + 1e-6f);
        float n1, n2;
        if (hid < 32) { n1 = x1 * rinv * qw1; n2 = x2 * rinv * qw2; }
        else          { n1 = x1 * rinv * kw1; n2 = x2 * rinv * kw2; }
        float o1 = n1 * cs - n2 * sn;
        float o2 = n2 * cs + n1 * sn;
        if (hid < 32) {
          const float QSC = 0.08838834764831845f * 1.4426950408889634f;
          __bf16* o = qo + ((size_t)tok * NQH + hid) * HD;
          o[lane] = (__bf16)(o1 * QSC);
          o[lane + 64] = (__bf16)(o2 * QSC);
        } else {
          __bf16* o = ko + ((size_t)tok * NKVH + (hid - 32)) * HD;
          o[lane] = (__bf16)o1;
          o[lane + 64] = (__bf16)o2;
        }
      }
    }
    // v-heads: block-wide coalesced transpose writes (token-contiguous)
#pragma unroll
    for (int hh = 0; hh < 3; ++hh) {
      const int hid = bn * 3 + hh;
      if (hid < 40) continue;
      const int kvh = hid - 40;
      const int tkn = tid & 127, dq = tid >> 7;   // 128 tokens x 4 d-lanes
#pragma unroll
      for (int dp = 0; dp < 32; ++dp) {
        int d = dp * 4 + dq;
        vto[((size_t)(kvh * 128 + d)) * T_TOK + bm * 128 + tkn] = tile[tkn][hh * 128 + d];
      }
    }
  }
}

// --- causal GQA flash attention (R13) + fused w_o transpose (blocks >= 512) --
__global__ __launch_bounds__(256, 2) void k_attn(const __bf16* __restrict__ Q,
                                                 const __bf16* __restrict__ K,
                                                 const __bf16* __restrict__ Vt,
                                                 __bf16* __restrict__ O,
                                                 const float* __restrict__ wo,
                                                 __bf16* __restrict__ wot) {
  __shared__ alignas(16) char lds[32768];
  const int tid = threadIdx.x;
  if (blockIdx.x >= 512) {
    const int tb = blockIdx.x - 512;            // 0..4095
    const int c0 = (tb & 63) * 64, r0 = (tb >> 6) * 64;
    float (*tile)[65] = (float(*)[65])lds;
    const int ty = tid >> 4, tx = tid & 15;
#pragma unroll
    for (int k = 0; k < 4; ++k) {
      float4 v = *(const float4*)&wo[(size_t)(r0 + ty + k * 16) * HID + c0 + tx * 4];
      tile[ty + k * 16][tx * 4 + 0] = v.x;
      tile[ty + k * 16][tx * 4 + 1] = v.y;
      tile[ty + k * 16][tx * 4 + 2] = v.z;
      tile[ty + k * 16][tx * 4 + 3] = v.w;
    }
    __syncthreads();
    const int c = tid >> 2, rq = tid & 3;
#pragma unroll
    for (int h = 0; h < 2; ++h) {
      bf16x8 o;
#pragma unroll
      for (int i = 0; i < 8; ++i) o[i] = (__bf16)tile[rq * 16 + h * 8 + i][c];
      *(bf16x8*)&wot[(size_t)(c0 + c) * HID + r0 + rq * 16 + h * 8] = o;
    }
    return;
  }
  const int bid = blockIdx.x;
  const int kvh = bid & 7;
  const int raw = bid >> 3;
  const int qc  = (raw < 32) ? 63 - raw : raw - 32;
  const int lane = tid & 63, w = tid >> 6;
  const int l31 = lane & 31, hi = lane >> 5;
  const int h  = kvh * 4 + w;
  const int q0 = qc * 32;
  const int qrow = q0 + l31;
  char* Ksb = lds;
  char* Vtb = lds + 16384;

  bf16x8 qf[8];
  {
    const __bf16* qp = Q + ((size_t)qrow * NQH + h) * HD + hi * 8;
#pragma unroll
    for (int dc = 0; dc < 8; ++dc)
      qf[dc] = *(const bf16x8*)(qp + dc * 16);
  }

  size_t ksrc[4], vsrc[4];
#pragma unroll
  for (int j = 0; j < 4; ++j) {
    int kr = w * 16 + j * 4 + (lane >> 4);
    ksrc[j] = ((size_t)kr * NKVH + kvh) * HD + (size_t)(((lane & 15) ^ (kr & 15)) * 8);
    int vr = w * 32 + j * 8 + (lane >> 3);
    vsrc[j] = ((size_t)(kvh * HD + vr)) * T_TOK + (size_t)(((lane & 7) ^ (vr & 7)) * 8);
  }

  float m_run = -3.0e38f, l_run = 0.f;
  f32x16 ot[4] = {};

  const int ntiles = (qc >> 1) + 1;
  for (int tt = 0; tt < ntiles; ++tt) {
    const int s0 = tt * 64;
#pragma unroll
    for (int j = 0; j < 4; ++j) {
      gll16(K + (size_t)s0 * (NKVH * HD) + ksrc[j], Ksb + (w * 4 + j) * 1024);
      gll16(Vt + (size_t)s0 + vsrc[j], Vtb + (w * 4 + j) * 1024);
    }
    __syncthreads();

    f32x16 sac[2] = {};
#pragma unroll
    for (int hf = 0; hf < 2; ++hf) {
      int krow = hf * 32 + l31;
#pragma unroll
      for (int dc = 0; dc < 8; ++dc) {
        bf16x8 kf = *(const bf16x8*)(Ksb + krow * 256 + (((dc * 2 + hi) ^ (krow & 15)) * 16));
        sac[hf] = __builtin_amdgcn_mfma_f32_32x32x16_bf16(kf, qf[dc], sac[hf], 0, 0, 0);
      }
    }

    float pv[32];
    if (s0 + 64 > q0) {
#pragma unroll
      for (int hf = 0; hf < 2; ++hf)
#pragma unroll
        for (int r = 0; r < 16; ++r) {
          int kvg = s0 + hf * 32 + (r & 3) + ((r >> 2) * 8) + hi * 4;
          pv[hf * 16 + r] = (kvg > qrow) ? -3.0e38f : sac[hf][r];
        }
    } else {
#pragma unroll
      for (int hf = 0; hf < 2; ++hf)
#pragma unroll
        for (int r = 0; r < 16; ++r) pv[hf * 16 + r] = sac[hf][r];
    }
    float t16[16];
#pragma unroll
    for (int i = 0; i < 16; ++i) t16[i] = fmaxf(pv[i], pv[i + 16]);
#pragma unroll
    for (int i = 0; i < 8; ++i) t16[i] = fmaxf(t16[i], t16[i + 8]);
#pragma unroll
    for (int i = 0; i < 4; ++i) t16[i] = fmaxf(t16[i], t16[i + 4]);
    float mt = fmaxf(fmaxf(t16[0], t16[1]), fmaxf(t16[2], t16[3]));
    mt = fmaxf(mt, __shfl_xor(mt, 32));
    if (!__all(mt - m_run <= 10.0f)) {
      float m_new = fmaxf(m_run, mt);
      float corr = exp2f(m_run - m_new);
      l_run *= corr;
#pragma unroll
      for (int dt = 0; dt < 4; ++dt)
#pragma unroll
        for (int r = 0; r < 16; ++r) ot[dt][r] *= corr;
      m_run = m_new;
    }
#pragma unroll
    for (int i = 0; i < 32; ++i) pv[i] = exp2f(pv[i] - m_run);
#pragma unroll
    for (int i = 0; i < 16; ++i) t16[i] = pv[i] + pv[i + 16];
#pragma unroll
    for (int i = 0; i < 8; ++i) t16[i] += t16[i + 8];
#pragma unroll
    for (int i = 0; i < 4; ++i) t16[i] += t16[i + 4];
    float rs = (t16[0] + t16[1]) + (t16[2] + t16[3]);
    rs += __shfl_xor(rs, 32);
    l_run += rs;

    uint32_t wds[16];
#pragma unroll
    for (int i = 0; i < 16; ++i) {
      uint32_t r;
      asm("v_cvt_pk_bf16_f32 %0, %1, %2" : "=v"(r) : "v"(pv[2 * i]), "v"(pv[2 * i + 1]));
      wds[i] = r;
    }
#pragma unroll
    for (int c = 0; c < 4; ++c) {
      const int base = (c >> 1) * 8 + (c & 1) * 4;
      uint32_t sa = hi ? wds[base + 0] : wds[base + 2];
      uint32_t sb = hi ? wds[base + 1] : wds[base + 3];
      uint32_t ra = __shfl_xor(sa, 32);
      uint32_t rb = __shfl_xor(sb, 32);
      union { uint32_t u[4]; bf16x8 v; } pf;
      pf.u[0] = hi ? ra : wds[base + 0];
      pf.u[1] = hi ? rb : wds[base + 1];
      pf.u[2] = hi ? wds[base + 2] : ra;
      pf.u[3] = hi ? wds[base + 3] : rb;
#pragma unroll
      for (int dt = 0; dt < 4; ++dt) {
        int vrow = dt * 32 + l31;
        bf16x8 vf = *(const bf16x8*)(Vtb + vrow * 128 + (((c * 2 + hi) ^ (vrow & 7)) * 16));
        ot[dt] = __builtin_amdgcn_mfma_f32_32x32x16_bf16(vf, pf.v, ot[dt], 0, 0, 0);
      }
    }
    __syncthreads();
  }

  float inv = 1.0f / l_run;
  char* Ob = Ksb + w * 8192;
#pragma unroll
  for (int dt = 0; dt < 4; ++dt)
#pragma unroll
    for (int r = 0; r < 16; ++r) {
      int d = dt * 32 + (r & 3) + ((r >> 2) * 8) + hi * 4;
      *(__bf16*)(Ob + l31 * 256 + ((d * 2) ^ ((l31 & 7) << 4))) = (__bf16)(ot[dt][r] * inv);
    }
  __builtin_amdgcn_s_barrier();
#pragma unroll
  for (int pass = 0; pass < 8; ++pass) {
    int q = pass * 4 + (lane >> 4);
    int ch = lane & 15;
    bf16x8 vvv = *(const bf16x8*)(Ob + q * 256 + ((ch ^ (q & 7)) * 16));
    *(bf16x8*)(O + ((size_t)(q0 + q) * NQH + h) * HD + ch * 8) = vvv;
  }
}

// ---------------- launch ----------------------------------------------------
extern "C" void kernel_launch(void* const* d_in, const int* in_sizes, int n_in,
                              void* d_out, int out_size, void* d_ws, size_t ws_size,
                              hipStream_t stream) {
  const int*   positions = (const int*)d_in[0];
  const float* hidden    = (const float*)d_in[1];
  const float* w_qkv     = (const float*)d_in[2];
  const float* w_o       = (const float*)d_in[3];
  const float* q_norm    = (const float*)d_in[4];
  const float* k_norm    = (const float*)d_in[5];
  float* out = (float*)d_out;

  char* ws = (char*)d_ws;
  __bf16* wqkv_t   = (__bf16*)ws;                  // [0, 50.3MB)
  __bf16* wo_t     = (__bf16*)(ws + 50331648);     // [50.3, 83.9)
  __bf16* hidden_b = (__bf16*)(ws + 83886080);     // [83.9, 100.7), dead after gemm1
  __bf16* qb  = (__bf16*)(ws + 100663296);         // q  [T][32][128] 16.8MB
  __bf16* kb  = (__bf16*)(ws + 117440512);         // k  [T][8][128]  4.2MB
  __bf16* vtb = (__bf16*)(ws + 121634816);         // Vt [8][128][T]  4.2MB
  __bf16* attn_o = hidden_b;                       // over dead hidden_b

  k_prep<<<dim3(8192 + 6144), 256, 0, stream>>>(hidden, hidden_b, w_qkv, wqkv_t);
  k_gemm8<6, __bf16, true><<<dim3(256), 512, 0, stream>>>(
      hidden_b, wqkv_t, nullptr, QKV_N, HID, positions, q_norm, k_norm, qb, kb, vtb);
  k_attn<<<dim3(512 + 4096), 256, 0, stream>>>(qb, kb, vtb, attn_o, w_o, wo_t);
  k_gemm8<4, float, false><<<dim3(256), 512, 0, stream>>>(
      attn_o, wo_t, out, HID, HID, nullptr, nullptr, nullptr, nullptr, nullptr, nullptr);
}

// Round 15
// 293.273 us; speedup vs baseline: 1.0259x; 1.0259x over previous
//
#include <hip/hip_runtime.h>
#include <cstdint>
#include <cstddef>

// ---------------- constants ----------------
#define T_TOK 2048
#define HID   4096
#define NQH   32
#define NKVH  8
#define HD    128
#define QKV_N 6144   // 4096 q + 1024 k + 1024 v

typedef __bf16 bf16x8 __attribute__((ext_vector_type(8)));
typedef __bf16 bf16x4 __attribute__((ext_vector_type(4)));
typedef float  f32x4  __attribute__((ext_vector_type(4)));
typedef float  f32x16 __attribute__((ext_vector_type(16)));

#define AS1 __attribute__((address_space(1)))
#define AS3 __attribute__((address_space(3)))

__device__ __forceinline__ void gll16(const void* g, void* l) {
  __builtin_amdgcn_global_load_lds((const AS1 void*)g, (AS3 void*)l, 16, 0, 0);
}

// ------- fused prologue: hidden fp32->bf16 convert + w_qkv transpose --------
// blocks < 8192: convert (exact cover of 2048*4096/4 float4s).
// blocks >= 8192: 64x64 transpose tile of w_qkv [4096][6144] -> wqkv_t bf16.
__global__ __launch_bounds__(256) void k_prep(const float* __restrict__ hidden,
                                              __bf16* __restrict__ hidden_b,
                                              const float* __restrict__ wqkv,
                                              __bf16* __restrict__ wqkv_t) {
  __shared__ float tile[64][65];
  const int tid = threadIdx.x;
  if (blockIdx.x < 8192) {
    int i = blockIdx.x * 256 + tid;
    float4 v = ((const float4*)hidden)[i];
    bf16x4 o;
    o[0] = (__bf16)v.x; o[1] = (__bf16)v.y; o[2] = (__bf16)v.z; o[3] = (__bf16)v.w;
    ((bf16x4*)hidden_b)[i] = o;
    return;
  }
  const int tb = blockIdx.x - 8192;          // 0..6143
  const int c0 = (tb % 96) * 64, r0 = (tb / 96) * 64;   // C=6144, R=4096
  const int ty = tid >> 4, tx = tid & 15;
#pragma unroll
  for (int k = 0; k < 4; ++k) {
    float4 v = *(const float4*)&wqkv[(size_t)(r0 + ty + k * 16) * QKV_N + c0 + tx * 4];
    tile[ty + k * 16][tx * 4 + 0] = v.x;
    tile[ty + k * 16][tx * 4 + 1] = v.y;
    tile[ty + k * 16][tx * 4 + 2] = v.z;
    tile[ty + k * 16][tx * 4 + 3] = v.w;
  }
  __syncthreads();
  const int c = tid >> 2, rq = tid & 3;
#pragma unroll
  for (int h = 0; h < 2; ++h) {
    bf16x8 o;
#pragma unroll
    for (int i = 0; i < 8; ++i) o[i] = (__bf16)tile[rq * 16 + h * 8 + i][c];
    *(bf16x8*)&wqkv_t[(size_t)(c0 + c) * HID + r0 + rq * 16 + h * 8] = o;
  }
}

// ---------------- 4-phase bf16 GEMM, BM=128 x BN=64*NFR (known-good) --------
template <int NFR, typename OUT>
__global__ __launch_bounds__(512, 2) void k_gemm8(const __bf16* __restrict__ A,
                                                  const __bf16* __restrict__ Bt,
                                                  OUT* __restrict__ C,
                                                  int N, int K) {
  constexpr int BN   = 64 * NFR;
  constexpr int WN   = 16 * NFR;
  constexpr int NB   = NFR / 2;
  constexpr int NH   = NFR / 2;
  constexpr int BREG = BN * 64;
  constexpr int BUFSZ = 16384 + 2 * BREG;
  __shared__ alignas(16) char ldsb[2 * BUFSZ];
  const int tid = threadIdx.x;
  const int lane = tid & 63, w = tid >> 6;
  const int l16 = lane & 15, lg = lane >> 4;
  const int wm = w >> 2, wn = w & 3;

  const int x = blockIdx.x & 7, idx = blockIdx.x >> 3;
  const int bm = (x & 1) * 8 + (idx & 7);
  const int bn = (x >> 1) * 4 + (idx >> 3);

  const int rA = tid >> 2, pA = tid & 3;
  const __bf16* asrc = A + (size_t)(bm * 128 + rA) * K + ((pA ^ ((rA >> 1) & 3)) * 8);
  const __bf16* bsrc = Bt + (size_t)(bn * BN + rA) * K + ((pA ^ ((rA >> 1) & 3)) * 8);

#define RA_(buf, mk) (ldsb + (buf) * BUFSZ + (mk) * 8192)
#define RB_(buf, mk) (ldsb + (buf) * BUFSZ + 16384 + (mk) * BREG)
#define STG_A(buf, mk, kk) { gll16(asrc + (kk) + (mk) * 32, RA_(buf, mk) + w * 1024); }
#define STG_B(buf, mk, kk) { _Pragma("unroll") \
    for (int j = 0; j < NB; ++j) \
      gll16(bsrc + (size_t)j * 128 * K + (kk) + (mk) * 32, RB_(buf, mk) + j * 8192 + w * 1024); }
#define FRAG(base, row) (*(const bf16x8*)((base) + (row) * 64 + ((lg ^ (((row) >> 1) & 3)) << 4)))
#define WAITN() { if constexpr (NFR == 6) asm volatile("s_waitcnt vmcnt(4)" ::: "memory"); \
                  else                    asm volatile("s_waitcnt vmcnt(3)" ::: "memory"); }

  f32x4 acc[4][NFR] = {};
  const int nkt = K >> 6;

  STG_A(0, 0, 0); STG_B(0, 0, 0); STG_A(0, 1, 0); STG_B(0, 1, 0);

  for (int t = 0; t < nkt - 1; ++t) {
    const int cur = t & 1, nxt = cur ^ 1;
    const int kn = (t + 1) * 64;
    bf16x8 af[4], bf_[NH];

    STG_A(nxt, 0, kn);
    WAITN();
    __builtin_amdgcn_s_barrier();
    __builtin_amdgcn_sched_barrier(0);
#pragma unroll
    for (int i = 0; i < 4; ++i) af[i] = FRAG(RA_(cur, 0), wm * 64 + i * 16 + l16);
#pragma unroll
    for (int n = 0; n < NH; ++n) bf_[n] = FRAG(RB_(cur, 0), wn * WN + n * 16 + l16);
    __builtin_amdgcn_s_setprio(1);
#pragma unroll
    for (int i = 0; i < 4; ++i)
#pragma unroll
      for (int n = 0; n < NH; ++n)
        acc[i][n] = __builtin_amdgcn_mfma_f32_16x16x32_bf16(af[i], bf_[n], acc[i][n], 0, 0, 0);
    __builtin_amdgcn_s_setprio(0);
    __builtin_amdgcn_s_barrier();

#pragma unroll
    for (int n = 0; n < NH; ++n) bf_[n] = FRAG(RB_(cur, 0), wn * WN + (NH + n) * 16 + l16);
    STG_B(nxt, 0, kn);
    __builtin_amdgcn_s_barrier();
    __builtin_amdgcn_s_setprio(1);
#pragma unroll
    for (int i = 0; i < 4; ++i)
#pragma unroll
      for (int n = 0; n < NH; ++n)
        acc[i][NH + n] = __builtin_amdgcn_mfma_f32_16x16x32_bf16(af[i], bf_[n], acc[i][NH + n], 0, 0, 0);
    __builtin_amdgcn_s_setprio(0);
    __builtin_amdgcn_s_barrier();

    STG_A(nxt, 1, kn);
    WAITN();
    __builtin_amdgcn_s_barrier();
    __builtin_amdgcn_sched_barrier(0);
#pragma unroll
    for (int i = 0; i < 4; ++i) af[i] = FRAG(RA_(cur, 1), wm * 64 + i * 16 + l16);
#pragma unroll
    for (int n = 0; n < NH; ++n) bf_[n] = FRAG(RB_(cur, 1), wn * WN + n * 16 + l16);
    __builtin_amdgcn_s_setprio(1);
#pragma unroll
    for (int i = 0; i < 4; ++i)
#pragma unroll
      for (int n = 0; n < NH; ++n)
        acc[i][n] = __builtin_amdgcn_mfma_f32_16x16x32_bf16(af[i], bf_[n], acc[i][n], 0, 0, 0);
    __builtin_amdgcn_s_setprio(0);
    __builtin_amdgcn_s_barrier();

#pragma unroll
    for (int n = 0; n < NH; ++n) bf_[n] = FRAG(RB_(cur, 1), wn * WN + (NH + n) * 16 + l16);
    STG_B(nxt, 1, kn);
    __builtin_amdgcn_s_barrier();
    __builtin_amdgcn_s_setprio(1);
#pragma unroll
    for (int i = 0; i < 4; ++i)
#pragma unroll
      for (int n = 0; n < NH; ++n)
        acc[i][NH + n] = __builtin_amdgcn_mfma_f32_16x16x32_bf16(af[i], bf_[n], acc[i][NH + n], 0, 0, 0);
    __builtin_amdgcn_s_setprio(0);
    __builtin_amdgcn_s_barrier();
  }

  asm volatile("s_waitcnt vmcnt(0)" ::: "memory");
  __builtin_amdgcn_s_barrier();
  __builtin_amdgcn_sched_barrier(0);
  {
    const int cur = (nkt - 1) & 1;
#pragma unroll
    for (int mk = 0; mk < 2; ++mk) {
      bf16x8 aa[4], bb[NFR];
#pragma unroll
      for (int i = 0; i < 4; ++i) aa[i] = FRAG(RA_(cur, mk), wm * 64 + i * 16 + l16);
#pragma unroll
      for (int n = 0; n < NFR; ++n) bb[n] = FRAG(RB_(cur, mk), wn * WN + n * 16 + l16);
#pragma unroll
      for (int i = 0; i < 4; ++i)
#pragma unroll
        for (int n = 0; n < NFR; ++n)
          acc[i][n] = __builtin_amdgcn_mfma_f32_16x16x32_bf16(aa[i], bb[n], acc[i][n], 0, 0, 0);
    }
  }
#undef RA_
#undef RB_
#undef STG_A
#undef STG_B
#undef FRAG
#undef WAITN

#pragma unroll
  for (int mi = 0; mi < 4; ++mi)
#pragma unroll
    for (int ni = 0; ni < NFR; ++ni) {
      int row = bm * 128 + wm * 64 + mi * 16 + lg * 4;
      int col = bn * BN + wn * WN + ni * 16 + l16;
#pragma unroll
      for (int r = 0; r < 4; ++r)
        C[(size_t)(row + r) * N + col] = (OUT)acc[mi][ni][r];
    }
}

// ------- per-token RMSNorm + RoPE (blocks < T_TOK) + fused V-transpose ------
// blocks >= T_TOK: vtrans tile path (qkv bf16 [T][6144] -> Vt [8][128][T]).
__global__ __launch_bounds__(256) void k_norm_rope(const __bf16* __restrict__ qkv,
                                                   const int* __restrict__ pos,
                                                   const float* __restrict__ qw,
                                                   const float* __restrict__ kw,
                                                   __bf16* __restrict__ qo,
                                                   __bf16* __restrict__ ko,
                                                   __bf16* __restrict__ vto) {
  __shared__ float tile[64][65];
  const int tid = threadIdx.x;
  if (blockIdx.x >= T_TOK) {
    // ---- vtrans path: tb in [0,512): d-half, t-tile, kvh ----
    const int tb = blockIdx.x - T_TOK;
    const int d0 = (tb & 1) * 64;
    const int t0 = ((tb >> 1) & 31) * 64;
    const int kvh = tb >> 6;
    const int ty = tid >> 4, tx = tid & 15;
#pragma unroll
    for (int k = 0; k < 4; ++k) {
      bf16x4 v = *(const bf16x4*)&qkv[(size_t)(t0 + ty + k * 16) * QKV_N + 5120 + kvh * 128 + d0 + tx * 4];
#pragma unroll
      for (int j = 0; j < 4; ++j) tile[ty + k * 16][tx * 4 + j] = (float)v[j];
    }
    __syncthreads();
    const int d = tid >> 2, tq = tid & 3;
#pragma unroll
    for (int h = 0; h < 2; ++h) {
      bf16x8 o;
#pragma unroll
      for (int i = 0; i < 8; ++i) o[i] = (__bf16)tile[tq * 16 + h * 8 + i][d];
      *(bf16x8*)&vto[((size_t)kvh * 128 + d0 + d) * T_TOK + t0 + tq * 16 + h * 8] = o;
    }
    return;
  }
  const int t = blockIdx.x;
  const int w = tid >> 6, i = tid & 63;
  const float fr = (float)pos[t] * expf((float)i * -0.21586735246819178f);
  const float cs = cosf(fr), sn = sinf(fr);
  const float qwi1 = qw[i], qwi2 = qw[i + 64];
  const float kwi1 = kw[i], kwi2 = kw[i + 64];
  const __bf16* base = qkv + (size_t)t * QKV_N;
#pragma unroll
  for (int s = 0; s < 10; ++s) {
    const int slot = w * 10 + s;
    const int off = (slot < 32) ? slot * 128 : 4096 + (slot - 32) * 128;
    float x1 = (float)base[off + i], x2 = (float)base[off + i + 64];
    float ss = x1 * x1 + x2 * x2;
#pragma unroll
    for (int m = 32; m >= 1; m >>= 1) ss += __shfl_xor(ss, m);
    float rinv = rsqrtf(ss * (1.0f / 128.0f) + 1e-6f);
    float n1, n2;
    if (slot < 32) { n1 = x1 * rinv * qwi1; n2 = x2 * rinv * qwi2; }
    else           { n1 = x1 * rinv * kwi1; n2 = x2 * rinv * kwi2; }
    float o1 = n1 * cs - n2 * sn;
    float o2 = n2 * cs + n1 * sn;
    if (slot < 32) {
      const float QSC = 0.08838834764831845f * 1.4426950408889634f;
      __bf16* o = qo + ((size_t)t * NQH + slot) * HD;
      o[i] = (__bf16)(o1 * QSC);
      o[i + 64] = (__bf16)(o2 * QSC);
    } else {
      __bf16* o = ko + ((size_t)t * NKVH + (slot - 32)) * HD;
      o[i] = (__bf16)o1;
      o[i + 64] = (__bf16)o2;
    }
  }
}

// --- causal GQA flash attention (R12) + fused w_o transpose (blocks >= 512) --
__global__ __launch_bounds__(256, 2) void k_attn(const __bf16* __restrict__ Q,
                                                 const __bf16* __restrict__ K,
                                                 const __bf16* __restrict__ Vt,
                                                 __bf16* __restrict__ O,
                                                 const float* __restrict__ wo,
                                                 __bf16* __restrict__ wot) {
  __shared__ alignas(16) char lds[32768];
  const int tid = threadIdx.x;
  if (blockIdx.x >= 512) {
    const int tb = blockIdx.x - 512;            // 0..4095
    const int c0 = (tb & 63) * 64, r0 = (tb >> 6) * 64;
    float (*tile)[65] = (float(*)[65])lds;
    const int ty = tid >> 4, tx = tid & 15;
#pragma unroll
    for (int k = 0; k < 4; ++k) {
      float4 v = *(const float4*)&wo[(size_t)(r0 + ty + k * 16) * HID + c0 + tx * 4];
      tile[ty + k * 16][tx * 4 + 0] = v.x;
      tile[ty + k * 16][tx * 4 + 1] = v.y;
      tile[ty + k * 16][tx * 4 + 2] = v.z;
      tile[ty + k * 16][tx * 4 + 3] = v.w;
    }
    __syncthreads();
    const int c = tid >> 2, rq = tid & 3;
#pragma unroll
    for (int h = 0; h < 2; ++h) {
      bf16x8 o;
#pragma unroll
      for (int i = 0; i < 8; ++i) o[i] = (__bf16)tile[rq * 16 + h * 8 + i][c];
      *(bf16x8*)&wot[(size_t)(c0 + c) * HID + r0 + rq * 16 + h * 8] = o;
    }
    return;
  }
  const int bid = blockIdx.x;
  const int kvh = bid & 7;
  const int raw = bid >> 3;
  const int qc  = (raw < 32) ? 63 - raw : raw - 32;
  const int lane = tid & 63, w = tid >> 6;
  const int l31 = lane & 31, hi = lane >> 5;
  const int h  = kvh * 4 + w;
  const int q0 = qc * 32;
  const int qrow = q0 + l31;
  char* Ksb = lds;
  char* Vtb = lds + 16384;

  bf16x8 qf[8];
  {
    const __bf16* qp = Q + ((size_t)qrow * NQH + h) * HD + hi * 8;
#pragma unroll
    for (int dc = 0; dc < 8; ++dc)
      qf[dc] = *(const bf16x8*)(qp + dc * 16);
  }

  size_t ksrc[4], vsrc[4];
#pragma unroll
  for (int j = 0; j < 4; ++j) {
    int kr = w * 16 + j * 4 + (lane >> 4);
    ksrc[j] = ((size_t)kr * NKVH + kvh) * HD + (size_t)(((lane & 15) ^ (kr & 15)) * 8);
    int vr = w * 32 + j * 8 + (lane >> 3);
    vsrc[j] = ((size_t)(kvh * HD + vr)) * T_TOK + (size_t)(((lane & 7) ^ (vr & 7)) * 8);
  }

  float m_run = -3.0e38f, l_run = 0.f;
  f32x16 ot[4] = {};

  const int ntiles = (qc >> 1) + 1;
  for (int tt = 0; tt < ntiles; ++tt) {
    const int s0 = tt * 64;
#pragma unroll
    for (int j = 0; j < 4; ++j) {
      gll16(K + (size_t)s0 * (NKVH * HD) + ksrc[j], Ksb + (w * 4 + j) * 1024);
      gll16(Vt + (size_t)s0 + vsrc[j], Vtb + (w * 4 + j) * 1024);
    }
    __syncthreads();

    f32x16 sac[2] = {};
#pragma unroll
    for (int hf = 0; hf < 2; ++hf) {
      int krow = hf * 32 + l31;
#pragma unroll
      for (int dc = 0; dc < 8; ++dc) {
        bf16x8 kf = *(const bf16x8*)(Ksb + krow * 256 + (((dc * 2 + hi) ^ (krow & 15)) * 16));
        sac[hf] = __builtin_amdgcn_mfma_f32_32x32x16_bf16(kf, qf[dc], sac[hf], 0, 0, 0);
      }
    }

    float pv[32];
    if (s0 + 64 > q0) {
#pragma unroll
      for (int hf = 0; hf < 2; ++hf)
#pragma unroll
        for (int r = 0; r < 16; ++r) {
          int kvg = s0 + hf * 32 + (r & 3) + ((r >> 2) * 8) + hi * 4;
          pv[hf * 16 + r] = (kvg > qrow) ? -3.0e38f : sac[hf][r];
        }
    } else {
#pragma unroll
      for (int hf = 0; hf < 2; ++hf)
#pragma unroll
        for (int r = 0; r < 16; ++r) pv[hf * 16 + r] = sac[hf][r];
    }
    float t16[16];
#pragma unroll
    for (int i = 0; i < 16; ++i) t16[i] = fmaxf(pv[i], pv[i + 16]);
#pragma unroll
    for (int i = 0; i < 8; ++i) t16[i] = fmaxf(t16[i], t16[i + 8]);
#pragma unroll
    for (int i = 0; i < 4; ++i) t16[i] = fmaxf(t16[i], t16[i + 4]);
    float mt = fmaxf(fmaxf(t16[0], t16[1]), fmaxf(t16[2], t16[3]));
    mt = fmaxf(mt, __shfl_xor(mt, 32));
    if (!__all(mt - m_run <= 10.0f)) {
      float m_new = fmaxf(m_run, mt);
      float corr = exp2f(m_run - m_new);
      l_run *= corr;
#pragma unroll
      for (int dt = 0; dt < 4; ++dt)
#pragma unroll
        for (int r = 0; r < 16; ++r) ot[dt][r] *= corr;
      m_run = m_new;
    }
#pragma unroll
    for (int i = 0; i < 32; ++i) pv[i] = exp2f(pv[i] - m_run);
#pragma unroll
    for (int i = 0; i < 16; ++i) t16[i] = pv[i] + pv[i + 16];
#pragma unroll
    for (int i = 0; i < 8; ++i) t16[i] += t16[i + 8];
#pragma unroll
    for (int i = 0; i < 4; ++i) t16[i] += t16[i + 4];
    float rs = (t16[0] + t16[1]) + (t16[2] + t16[3]);
    rs += __shfl_xor(rs, 32);
    l_run += rs;

    uint32_t wds[16];
#pragma unroll
    for (int i = 0; i < 16; ++i) {
      uint32_t r;
      asm("v_cvt_pk_bf16_f32 %0, %1, %2" : "=v"(r) : "v"(pv[2 * i]), "v"(pv[2 * i + 1]));
      wds[i] = r;
    }
#pragma unroll
    for (int c = 0; c < 4; ++c) {
      const int base = (c >> 1) * 8 + (c & 1) * 4;
      uint32_t sa = hi ? wds[base + 0] : wds[base + 2];
      uint32_t sb = hi ? wds[base + 1] : wds[base + 3];
      uint32_t ra = __shfl_xor(sa, 32);
      uint32_t rb = __shfl_xor(sb, 32);
      union { uint32_t u[4]; bf16x8 v; } pf;
      pf.u[0] = hi ? ra : wds[base + 0];
      pf.u[1] = hi ? rb : wds[base + 1];
      pf.u[2] = hi ? wds[base + 2] : ra;
      pf.u[3] = hi ? wds[base + 3] : rb;
#pragma unroll
      for (int dt = 0; dt < 4; ++dt) {
        int vrow = dt * 32 + l31;
        bf16x8 vf = *(const bf16x8*)(Vtb + vrow * 128 + (((c * 2 + hi) ^ (vrow & 7)) * 16));
        ot[dt] = __builtin_amdgcn_mfma_f32_32x32x16_bf16(vf, pf.v, ot[dt], 0, 0, 0);
      }
    }
    __syncthreads();
  }

  float inv = 1.0f / l_run;
  char* Ob = Ksb + w * 8192;
#pragma unroll
  for (int dt = 0; dt < 4; ++dt)
#pragma unroll
    for (int r = 0; r < 16; ++r) {
      int d = dt * 32 + (r & 3) + ((r >> 2) * 8) + hi * 4;
      *(__bf16*)(Ob + l31 * 256 + ((d * 2) ^ ((l31 & 7) << 4))) = (__bf16)(ot[dt][r] * inv);
    }
  __builtin_amdgcn_s_barrier();
#pragma unroll
  for (int pass = 0; pass < 8; ++pass) {
    int q = pass * 4 + (lane >> 4);
    int ch = lane & 15;
    bf16x8 vvv = *(const bf16x8*)(Ob + q * 256 + ((ch ^ (q & 7)) * 16));
    *(bf16x8*)(O + ((size_t)(q0 + q) * NQH + h) * HD + ch * 8) = vvv;
  }
}

// ---------------- launch ----------------------------------------------------
extern "C" void kernel_launch(void* const* d_in, const int* in_sizes, int n_in,
                              void* d_out, int out_size, void* d_ws, size_t ws_size,
                              hipStream_t stream) {
  const int*   positions = (const int*)d_in[0];
  const float* hidden    = (const float*)d_in[1];
  const float* w_qkv     = (const float*)d_in[2];
  const float* w_o       = (const float*)d_in[3];
  const float* q_norm    = (const float*)d_in[4];
  const float* k_norm    = (const float*)d_in[5];
  float* out = (float*)d_out;

  char* ws = (char*)d_ws;
  __bf16* wqkv_t   = (__bf16*)ws;                  // 50.3MB, dead after gemm1
  __bf16* wo_t     = (__bf16*)(ws + 50331648);     // 33.6MB
  __bf16* hidden_b = (__bf16*)(ws + 83886080);     // 16.8MB, dead after gemm1
  __bf16* qkvb     = (__bf16*)(ws + 100663296);    // 25.2MB bf16 [2048][6144]
  __bf16* qb  = (__bf16*)ws;                       // q  [T][32][128] (over dead wqkv_t)
  __bf16* kb  = (__bf16*)(ws + 16777216);          // k  [T][8][128]
  __bf16* vtb = (__bf16*)(ws + 20971520);          // Vt [8][128][T]
  __bf16* attn_o = hidden_b;                       // over dead hidden_b

  k_prep<<<dim3(8192 + 6144), 256, 0, stream>>>(hidden, hidden_b, w_qkv, wqkv_t);
  k_gemm8<6, __bf16><<<dim3(256), 512, 0, stream>>>(hidden_b, wqkv_t, qkvb, QKV_N, HID);
  k_norm_rope<<<dim3(T_TOK + 512), 256, 0, stream>>>(qkvb, positions, q_norm, k_norm, qb, kb, vtb);
  k_attn<<<dim3(512 + 4096), 256, 0, stream>>>(qb, kb, vtb, attn_o, w_o, wo_t);
  k_gemm8<4, float><<<dim3(256), 512, 0, stream>>>(attn_o, wo_t, out, HID, HID);
}